// Round 13
// baseline (607.540 us; speedup 1.0000x reference)
//
#include <hip/hip_runtime.h>

// Problem constants (from reference)
constexpr int B_ = 16;
constexpr int NV = 20000;      // N vertices
constexpr int KN = 16;         // K neighbors
constexpr int LAT = 256;       // LATENT
constexpr int HID = 1024;      // HIDDEN
constexpr int N3 = 60000;      // N*3
constexpr int RCAP = 64;       // reverse-adjacency capacity
constexpr int NCHUNK = 8;      // K-split for mlp2 (1024/128)
constexpr float INV_NK = 1.0f / (20000.0f * 16.0f);

// W2 touch: 938 blocks x 256KB stream W2 into the memory-side LLC
constexpr int NT = 938;                        // ceil(15360000 f4 / 16384)
constexpr size_t W2_F4 = 15360000;             // 1024*60000/4

// Workspace layout (float units)
constexpr size_t H_OFF      = 0;                             // h      [16][1024]
constexpr size_t XQ_OFF     = H_OFF + B_ * HID;              // xq     [20000][6][16] (x0..x2,q0..q2)
constexpr size_t GRECON_OFF = XQ_OFF + (size_t)NV * 96;      // g_recon[16][60000]
constexpr size_t GH_OFF     = GRECON_OFF + (size_t)B_ * N3;  // g_h    [16][1024]
constexpr size_t OWNG_OFF   = GH_OFF + B_ * HID;             // ownG   [20000][16][4]
constexpr size_t GEDGE_OFF  = OWNG_OFF + (size_t)NV * 64;    // gEdge  [20000][16][16][4]
constexpr size_t RCOUNT_OFF = GEDGE_OFF + (size_t)NV * KN * 64; // int [20000]
constexpr size_t RLIST_OFF  = RCOUNT_OFF + NV;               // int   [20000][64]
constexpr size_t PART_OFF   = RLIST_OFF + (size_t)NV * RCAP; // [8][60000][16]

__device__ __forceinline__ void atomAddF(float* p, float v) {
  unsafeAtomicAdd(p, v);   // hardware global_atomic_add_f32 on gfx950
}

// stream 256KB of W2 (independent loads, high MLP) and dump into dead scratch
__device__ __forceinline__ void touchW2(const float* __restrict__ W2,
                                        float* __restrict__ dump,
                                        int tb, int tid) {
  const float4* w4 = (const float4*)W2;
  float s = 0.0f;
  size_t base = (size_t)tb * 16384 + tid;
  #pragma unroll 8
  for (int i = 0; i < 64; ++i) {
    size_t idx = base + (size_t)i * 256;
    if (idx < W2_F4) {
      float4 v = w4[idx];
      s += v.x + v.y + v.z + v.w;
    }
  }
  dump[tb * 256 + tid] = s;                    // keeps loads live; part is dead here
}

// ---------------- fused prep: xpose -> xq, mlp1, zero gh/out/rcount, W2 touch ----------------
// block ranges: [0,938) xpose, [938,1002) mlp1, [1002,1006) zero gh,
//               1006 zero out, [1007,1086) zero rcount, [1086,2024) W2 touch
__global__ __launch_bounds__(256) void k_prep(
    const float* __restrict__ xyz, const float* __restrict__ code,
    const float* __restrict__ W1, const float* __restrict__ b1,
    const float* __restrict__ W2,
    float* __restrict__ xq, float* __restrict__ h,
    float* __restrict__ gh, float* __restrict__ out,
    int* __restrict__ rcount, float* __restrict__ dump) {
  const int bid = blockIdx.x, tid = threadIdx.x;
  if (bid < 938) {                              // transpose xyz -> xq x-part
    __shared__ float sm[64][17];
    const int n30 = bid * 64;
    {
      const int n3l = tid & 63, bq = tid >> 6;
      #pragma unroll
      for (int p = 0; p < 4; ++p) {
        int b = p * 4 + bq;
        if (n30 + n3l < N3) sm[n3l][b] = xyz[(size_t)b * N3 + n30 + n3l];
      }
    }
    __syncthreads();
    {
      const int b = tid & 15, nq = tid >> 4;
      #pragma unroll
      for (int p = 0; p < 4; ++p) {
        int n3 = n30 + p * 16 + nq;
        if (n3 < N3) {
          int n = n3 / 3, c = n3 - n * 3;
          xq[(size_t)n * 96 + c * 16 + b] = sm[p * 16 + nq][b];
        }
      }
    }
  } else if (bid < 1002) {                      // h = relu(code @ W1 + b1)
    int t = (bid - 938) * 256 + tid;            // 0..16383
    int b = t >> 10, hd = t & 1023;
    const float* c = code + b * LAT;
    float acc = b1[hd];
    #pragma unroll 4
    for (int l = 0; l < LAT; ++l) acc += c[l] * W1[l * HID + hd];
    h[t] = fmaxf(acc, 0.0f);
  } else if (bid < 1006) {                      // zero gh (16384 floats)
    int base = (bid - 1002) * 4096 + tid;
    #pragma unroll
    for (int r = 0; r < 16; ++r) gh[base + r * 256] = 0.0f;
  } else if (bid == 1006) {                     // zero out (16 + 4096 floats)
    for (int i = tid; i < B_ + B_ * LAT; i += 256) out[i] = 0.0f;
  } else if (bid < 1086) {                      // zero rcount (20000 ints)
    int i = (bid - 1007) * 256 + tid;
    if (i < NV) rcount[i] = 0;
  } else {                                      // W2 -> LLC before k_mlp2f
    touchW2(W2, dump, bid - 1086, tid);
  }
}

// ---------------- mlp2 partials + reverse-adjacency fill (independent work) ----------------
// blocks [0,472): part[chunk][j][b] = h-chunk @ W2-chunk ; blocks [472,1722): fill
__global__ __launch_bounds__(256) void k_mlp2f(
    const float* __restrict__ h, const float* __restrict__ W2,
    float* __restrict__ part,
    const int* __restrict__ nbrs, const int* __restrict__ nnbr,
    int* __restrict__ rcount, int* __restrict__ rlist) {
  const int bid = blockIdx.x;
  const int tid = threadIdx.x;
  if (bid >= 472) {                             // reverse adjacency fill
    int e = (bid - 472) * 256 + tid;            // 0..319999
    int n = e >> 4, k = e & 15;
    if (k < nnbr[n]) {
      int v = nbrs[e];
      int slot = atomicAdd(&rcount[v], 1);
      if (slot < RCAP) rlist[v * RCAP + slot] = e;
    }
    return;
  }
  const int bx = bid % 59, by = bid / 59;
  __shared__ float hs[16][128];
  const int hd0 = by * 128;
  #pragma unroll
  for (int r = 0; r < 8; ++r) {                 // stage h[0:16][hd0:hd0+128]
    int idx = r * 256 + tid;
    int bb = idx >> 7, cc = idx & 127;
    hs[bb][cc] = h[bb * HID + hd0 + cc];
  }
  __syncthreads();

  const int j4 = bx * 1024 + tid * 4;
  if (j4 >= N3) return;

  float4 acc[16];
  #pragma unroll
  for (int b = 0; b < 16; ++b) acc[b] = make_float4(0.f, 0.f, 0.f, 0.f);

  const float* wp = W2 + (size_t)hd0 * N3 + j4;
  float4 w0 = *(const float4*)(wp);
  float4 w1 = *(const float4*)(wp + (size_t)N3);
  float4 w2 = *(const float4*)(wp + (size_t)2 * N3);
  float4 w3 = *(const float4*)(wp + (size_t)3 * N3);

  for (int g = 0; g < 32; ++g) {
    const float* np = wp + (size_t)4 * N3;
    float4 n0, n1, n2, n3;
    if (g < 31) {                               // prefetch next 4 rows
      n0 = *(const float4*)(np);
      n1 = *(const float4*)(np + (size_t)N3);
      n2 = *(const float4*)(np + (size_t)2 * N3);
      n3 = *(const float4*)(np + (size_t)3 * N3);
    }
    #pragma unroll
    for (int b = 0; b < 16; ++b) {
      float4 hb = *(const float4*)&hs[b][g * 4];   // broadcast ds_read_b128
      acc[b].x += hb.x * w0.x + hb.y * w1.x + hb.z * w2.x + hb.w * w3.x;
      acc[b].y += hb.x * w0.y + hb.y * w1.y + hb.z * w2.y + hb.w * w3.y;
      acc[b].z += hb.x * w0.z + hb.y * w1.z + hb.z * w2.z + hb.w * w3.z;
      acc[b].w += hb.x * w0.w + hb.y * w1.w + hb.z * w2.w + hb.w * w3.w;
    }
    wp = np; w0 = n0; w1 = n1; w2 = n2; w3 = n3;
  }

  float ac[4][16];
  #pragma unroll
  for (int b = 0; b < 16; ++b) {
    ac[0][b] = acc[b].x; ac[1][b] = acc[b].y;
    ac[2][b] = acc[b].z; ac[3][b] = acc[b].w;
  }
  float* pbase = part + ((size_t)by * N3 + j4) * 16;
  #pragma unroll
  for (int jj = 0; jj < 4; ++jj)
    #pragma unroll
    for (int q = 0; q < 4; ++q)
      *(float4*)(pbase + jj * 16 + q * 4) = make_float4(
          ac[jj][q*4+0], ac[jj][q*4+1], ac[jj][q*4+2], ac[jj][q*4+3]);
}

// ---------------- xq q-part[j][b] = sum_c part[c][j][b] + b2[j] ----------------
__global__ __launch_bounds__(256) void k_reduce(
    const float* __restrict__ part, const float* __restrict__ b2,
    float* __restrict__ xq) {
  int t = blockIdx.x * 256 + threadIdx.x;       // one float4 each
  if (t >= N3 * 16 / 4) return;
  size_t pos = (size_t)t * 4;
  int j = t >> 2, bq = (t & 3) * 4;
  float4 s = *(const float4*)(part + pos);
  #pragma unroll
  for (int c = 1; c < NCHUNK; ++c) {
    float4 p = *(const float4*)(part + (size_t)c * N3 * 16 + pos);
    s.x += p.x; s.y += p.y; s.z += p.z; s.w += p.w;
  }
  float bias = b2[j];
  s.x += bias; s.y += bias; s.z += bias; s.w += bias;
  int n = j / 3, c = j - n * 3;
  *(float4*)(xq + (size_t)n * 96 + (3 + c) * 16 + bq) = s;
}

// ---------------- per-vertex: S, Jacobi->R, energy, per-edge grad store ----------------
// Array-free two-pass: pass 1 accumulates S only; pass 2 RE-GATHERS xq/nbrs/wmat
// (L2/L3-hot) and computes resid/energy/grads. VGPR ~90 -> 4 waves/EU residency.
__global__ __launch_bounds__(256, 4) void k_rot(
    const float* __restrict__ xq,
    const float* __restrict__ wmat, const float* __restrict__ area,
    const int* __restrict__ nbrs, const int* __restrict__ nnbr,
    float* __restrict__ ownG, float* __restrict__ gEdge,
    float* __restrict__ energy) {
  __shared__ float red[64];
  const int tid = threadIdx.x;
  const int b = tid & 15, nl = tid >> 4;
  const int n = blockIdx.x * 16 + nl;           // grid 1250 -> exactly 20000
  const int nn = nnbr[n];
  const float ar = area[n];
  const float* xqn = xq + (size_t)n * 96 + b;
  const float x0 = xqn[0],  x1 = xqn[16], x2 = xqn[32];
  const float q0 = xqn[48], q1 = xqn[64], q2 = xqn[80];

  // pass 1: covariance S (no per-k state kept)
  float S00=0,S01=0,S02=0,S10=0,S11=0,S12=0,S20=0,S21=0,S22=0;
  #pragma unroll
  for (int k = 0; k < KN; ++k) {
    if (k < nn) {
      int m = nbrs[n * KN + k];                 // broadcast across 16 b-lanes
      float w = wmat[n * KN + k];
      const float* mp = xq + (size_t)m * 96 + b;
      float dx = x0 - mp[0],  dy = x1 - mp[16], dz = x2 - mp[32];
      float ex = q0 - mp[48], ey = q1 - mp[64], ez = q2 - mp[80];
      S00 += w*dx*ex; S01 += w*dx*ey; S02 += w*dx*ez;
      S10 += w*dy*ex; S11 += w*dy*ey; S12 += w*dy*ez;
      S20 += w*dz*ex; S21 += w*dz*ey; S22 += w*dz*ez;
    }
  }

  float A00 = S00*S00 + S10*S10 + S20*S20;
  float A01 = S00*S01 + S10*S11 + S20*S21;
  float A02 = S00*S02 + S10*S12 + S20*S22;
  float A11 = S01*S01 + S11*S11 + S21*S21;
  float A12 = S01*S02 + S11*S12 + S21*S22;
  float A22 = S02*S02 + S12*S12 + S22*S22;
  float V00=1,V01=0,V02=0, V10=0,V11=1,V12=0, V20=0,V21=0,V22=1;

  auto rot = [&](float& app, float& aqq, float& apq, float& arp, float& arq,
                 float& vp0, float& vp1, float& vp2,
                 float& vq0, float& vq1, float& vq2) {
    float a = apq;
    if (fabsf(a) > 1e-37f) {
      float tau = (aqq - app) * 0.5f / a;
      float t = copysignf(1.0f, tau) / (fabsf(tau) + sqrtf(1.0f + tau * tau));
      float c = rsqrtf(1.0f + t * t);
      float s = t * c;
      float napp = c*c*app - 2.0f*s*c*a + s*s*aqq;
      float naqq = s*s*app + 2.0f*s*c*a + c*c*aqq;
      app = napp; aqq = naqq; apq = 0.0f;
      float rp = arp, rq = arq;
      arp = c*rp - s*rq; arq = s*rp + c*rq;
      float t0, t1;
      t0=vp0; t1=vq0; vp0 = c*t0 - s*t1; vq0 = s*t0 + c*t1;
      t0=vp1; t1=vq1; vp1 = c*t0 - s*t1; vq1 = s*t0 + c*t1;
      t0=vp2; t1=vq2; vp2 = c*t0 - s*t1; vq2 = s*t0 + c*t1;
    }
  };
  #pragma unroll
  for (int sweep = 0; sweep < 6; ++sweep) {
    rot(A00,A11,A01, A02,A12, V00,V10,V20, V01,V11,V21);
    rot(A00,A22,A02, A01,A12, V00,V10,V20, V02,V12,V22);
    rot(A11,A22,A12, A01,A02, V01,V11,V21, V02,V12,V22);
  }
  auto sw = [](float& a, float& c) { float t = a; a = c; c = t; };
  if (A00 < A11) { sw(A00,A11); sw(V00,V01); sw(V10,V11); sw(V20,V21); }
  if (A00 < A22) { sw(A00,A22); sw(V00,V02); sw(V10,V12); sw(V20,V22); }
  if (A11 < A22) { sw(A11,A22); sw(V01,V02); sw(V11,V12); sw(V21,V22); }

  float v1x=V00, v1y=V10, v1z=V20;
  float v2x=V01, v2y=V11, v2z=V21;

  float u1x = S00*v1x + S01*v1y + S02*v1z;
  float u1y = S10*v1x + S11*v1y + S12*v1z;
  float u1z = S20*v1x + S21*v1y + S22*v1z;
  float s1sq = u1x*u1x + u1y*u1y + u1z*u1z;
  if (s1sq > 1e-30f) { float r = rsqrtf(s1sq); u1x*=r; u1y*=r; u1z*=r; }
  else { u1x = 1.0f; u1y = 0.0f; u1z = 0.0f; }

  float u2x = S00*v2x + S01*v2y + S02*v2z;
  float u2y = S10*v2x + S11*v2y + S12*v2z;
  float u2z = S20*v2x + S21*v2y + S22*v2z;
  float pr = u2x*u1x + u2y*u1y + u2z*u1z;
  u2x -= pr*u1x; u2y -= pr*u1y; u2z -= pr*u1z;
  float s2sq = u2x*u2x + u2y*u2y + u2z*u2z;
  if (s2sq > 1e-12f * s1sq + 1e-30f) {
    float r = rsqrtf(s2sq); u2x*=r; u2y*=r; u2z*=r;
  } else {
    float ex_ = (fabsf(u1x) < 0.9f) ? 1.0f : 0.0f;
    float ey_ = 1.0f - ex_;
    float pp = ex_*u1x + ey_*u1y;
    u2x = ex_ - pp*u1x; u2y = ey_ - pp*u1y; u2z = -pp*u1z;
    float r = rsqrtf(u2x*u2x + u2y*u2y + u2z*u2z);
    u2x*=r; u2y*=r; u2z*=r;
  }
  float u3x = u1y*u2z - u1z*u2y, u3y = u1z*u2x - u1x*u2z, u3z = u1x*u2y - u1y*u2x;
  float v3x = v1y*v2z - v1z*v2y, v3y = v1z*v2x - v1x*v2z, v3z = v1x*v2y - v1y*v2x;

  float R00 = v1x*u1x + v2x*u2x + v3x*u3x;
  float R01 = v1x*u1y + v2x*u2y + v3x*u3y;
  float R02 = v1x*u1z + v2x*u2z + v3x*u3z;
  float R10 = v1y*u1x + v2y*u2x + v3y*u3x;
  float R11 = v1y*u1y + v2y*u2y + v3y*u3y;
  float R12 = v1y*u1z + v2y*u2z + v3y*u3z;
  float R20 = v1z*u1x + v2z*u2x + v3z*u3x;
  float R21 = v1z*u1y + v2z*u2y + v3z*u3y;
  float R22 = v1z*u1z + v2z*u2z + v3z*u3z;

  // pass 2: re-gather (cache-hot), residuals, energy, per-edge + own grads
  float esum = 0, go0 = 0, go1 = 0, go2 = 0;
  const float gf = 2.0f * ar * INV_NK;
  float* geb = gEdge + (size_t)n * 1024 + b * 4;   // [n][k][b][4]
  #pragma unroll
  for (int k = 0; k < KN; ++k) {
    if (k < nn) {
      int m = nbrs[n * KN + k];
      float w = wmat[n * KN + k];
      const float* mp = xq + (size_t)m * 96 + b;
      float dx = x0 - mp[0],  dy = x1 - mp[16], dz = x2 - mp[32];
      float ex = q0 - mp[48], ey = q1 - mp[64], ez = q2 - mp[80];
      float rx = ex - (R00*dx + R01*dy + R02*dz);
      float ry = ey - (R10*dx + R11*dy + R12*dz);
      float rz = ez - (R20*dx + R21*dy + R22*dz);
      esum += w * (rx*rx + ry*ry + rz*rz);
      float gc = gf * w;
      float gx = gc*rx, gy = gc*ry, gz = gc*rz;
      go0 += gx; go1 += gy; go2 += gz;
      *(float4*)(geb + k * 64) = make_float4(gx, gy, gz, 0.0f);
    }
  }
  esum *= ar * INV_NK;

  // own-gradient store: ownG[n][b][4]
  *(float4*)(ownG + (size_t)n * 64 + b * 4) = make_float4(go0, go1, go2, 0.0f);

  esum += __shfl_down(esum, 32);
  esum += __shfl_down(esum, 16);
  int wave = tid >> 6, lane = tid & 63;
  if (lane < 16) red[wave * 16 + lane] = esum;
  __syncthreads();
  if (tid < 16) atomAddF(&energy[tid], red[tid] + red[16 + tid] + red[32 + tid] + red[48 + tid]);
}

// ---------------- gather incoming edge grads + W2 re-touch before mlp2_bwd ----------------
// blocks [0,1250): scatter ; blocks [1250,2188): W2 touch (concurrent, reads only)
__global__ __launch_bounds__(256) void k_scatter(
    const float* __restrict__ gEdge, const float* __restrict__ ownG,
    const int* __restrict__ rcount, const int* __restrict__ rlist,
    const float* __restrict__ W2, float* __restrict__ dump,
    float* __restrict__ grecon) {
  const int bid = blockIdx.x;
  const int tid = threadIdx.x;
  if (bid >= 1250) {                            // W2 -> LLC before k_mlp2_bwd
    touchW2(W2, dump, bid - 1250, tid);
    return;
  }
  int t = bid * 256 + tid;                      // 20000*16 threads
  int v = t >> 4, b = t & 15;
  const float4 og = *(const float4*)(ownG + (size_t)v * 64 + b * 4);
  float g0 = og.x, g1 = og.y, g2 = og.z;
  int deg = min(rcount[v], RCAP);
  const int* rl = rlist + v * RCAP;
  int i = 0;
  for (; i + 3 < deg; i += 4) {                 // 4-wide for ILP
    int e0 = rl[i], e1 = rl[i + 1], e2 = rl[i + 2], e3 = rl[i + 3];
    float4 p0 = *(const float4*)(gEdge + (size_t)e0 * 64 + b * 4);
    float4 p1 = *(const float4*)(gEdge + (size_t)e1 * 64 + b * 4);
    float4 p2 = *(const float4*)(gEdge + (size_t)e2 * 64 + b * 4);
    float4 p3 = *(const float4*)(gEdge + (size_t)e3 * 64 + b * 4);
    g0 -= (p0.x + p1.x) + (p2.x + p3.x);
    g1 -= (p0.y + p1.y) + (p2.y + p3.y);
    g2 -= (p0.z + p1.z) + (p2.z + p3.z);
  }
  for (; i < deg; ++i) {
    int e = rl[i];
    float4 p = *(const float4*)(gEdge + (size_t)e * 64 + b * 4);
    g0 -= p.x; g1 -= p.y; g2 -= p.z;
  }
  float* gq = grecon + (size_t)b * N3 + v * 3;
  gq[0] = g0; gq[1] = g1; gq[2] = g2;
}

// ---------------- g_h = g_recon @ W2^T (round-1 body, best measured ~115 us) -------------
__global__ __launch_bounds__(256, 2) void k_mlp2_bwd(
    const float* __restrict__ gr, const float* __restrict__ W2,
    float* __restrict__ gh) {
  const int tid = threadIdx.x;
  const int lane = tid & 63;
  const int wv = tid >> 6;
  const int laneJ = lane & 15, laneR = lane >> 4;
  const int row0 = blockIdx.y * 32 + wv * 8 + laneR * 2;   // rows row0, row0+1

  float4 acc0[16], acc1[16];
  #pragma unroll
  for (int b = 0; b < 16; ++b) {
    acc0[b] = make_float4(0.f, 0.f, 0.f, 0.f);
    acc1[b] = make_float4(0.f, 0.f, 0.f, 0.f);
  }

  const int jbase = blockIdx.x * 64 + laneJ * 4;
  const float* w2r0 = W2 + (size_t)row0 * N3;
  const float* w2r1 = W2 + (size_t)(row0 + 1) * N3;

  for (int it = 0; it < 59; ++it) {
    int j = jbase + it * 1024;
    if (j < N3) {
      float4 w0 = *(const float4*)(w2r0 + j);
      float4 w1 = *(const float4*)(w2r1 + j);
      #pragma unroll
      for (int b = 0; b < 16; ++b) {
        float4 g = *(const float4*)(gr + (size_t)b * N3 + j);
        acc0[b].x += g.x * w0.x; acc0[b].y += g.y * w0.y;
        acc0[b].z += g.z * w0.z; acc0[b].w += g.w * w0.w;
        acc1[b].x += g.x * w1.x; acc1[b].y += g.y * w1.y;
        acc1[b].z += g.z * w1.z; acc1[b].w += g.w * w1.w;
      }
    }
  }

  float s0[16], s1[16];
  #pragma unroll
  for (int b = 0; b < 16; ++b) {
    s0[b] = (acc0[b].x + acc0[b].y) + (acc0[b].z + acc0[b].w);
    s1[b] = (acc1[b].x + acc1[b].y) + (acc1[b].z + acc1[b].w);
  }
  #pragma unroll
  for (int m = 1; m <= 8; m <<= 1) {
    #pragma unroll
    for (int b = 0; b < 16; ++b) {
      s0[b] += __shfl_xor(s0[b], m);
      s1[b] += __shfl_xor(s1[b], m);
    }
  }
  if (laneJ == 0) {
    #pragma unroll
    for (int b = 0; b < 16; ++b) {
      atomAddF(&gh[b * HID + row0], s0[b]);
      atomAddF(&gh[b * HID + row0 + 1], s1[b]);
    }
  }
}

// ---------------- g_code = (g_h * relu') @ W1^T ----------------
__global__ __launch_bounds__(256) void k_mlp1_bwd(
    const float* __restrict__ gh, const float* __restrict__ h,
    const float* __restrict__ W1, float* __restrict__ gcode) {
  __shared__ float gm[128];
  const int b = blockIdx.x;
  const int hd0 = blockIdx.y * 128;
  const int l = threadIdx.x;
  if (l < 128) {
    float g = gh[b * HID + hd0 + l];
    gm[l] = (h[b * HID + hd0 + l] > 0.0f) ? g : 0.0f;
  }
  __syncthreads();
  const float4* wp = (const float4*)(W1 + (size_t)l * HID + hd0);
  float acc = 0.0f;
  #pragma unroll
  for (int i = 0; i < 32; ++i) {
    float4 w4 = wp[i];
    acc += w4.x * gm[i*4+0] + w4.y * gm[i*4+1] + w4.z * gm[i*4+2] + w4.w * gm[i*4+3];
  }
  atomAddF(&gcode[b * LAT + l], acc);
}

extern "C" void kernel_launch(void* const* d_in, const int* in_sizes, int n_in,
                              void* d_out, int out_size, void* d_ws, size_t ws_size,
                              hipStream_t stream) {
  const float* code = (const float*)d_in[0];
  const float* W1   = (const float*)d_in[1];
  const float* b1   = (const float*)d_in[2];
  const float* W2   = (const float*)d_in[3];
  const float* b2   = (const float*)d_in[4];
  const float* xyz  = (const float*)d_in[5];
  const float* wmat = (const float*)d_in[6];
  const float* area = (const float*)d_in[7];
  const int* nbrs   = (const int*)d_in[8];
  const int* nnbr   = (const int*)d_in[9];

  float* out = (float*)d_out;           // [16] meanEnergy, [16*256] code_grad
  float* ws = (float*)d_ws;
  float* h      = ws + H_OFF;
  float* xq     = ws + XQ_OFF;
  float* grecon = ws + GRECON_OFF;
  float* gh     = ws + GH_OFF;
  float* ownG   = ws + OWNG_OFF;
  float* gEdge  = ws + GEDGE_OFF;
  int*   rcount = (int*)(ws + RCOUNT_OFF);
  int*   rlist  = (int*)(ws + RLIST_OFF);
  float* part   = ws + PART_OFF;        // also used as dead scratch for touch dumps

  // 7 dispatches; W2 LLC-touch blocks fused into k_prep and k_scatter
  k_prep<<<dim3(1086 + NT), dim3(256), 0, stream>>>(
      xyz, code, W1, b1, W2, xq, h, gh, out, rcount, part);
  k_mlp2f<<<dim3(472 + NV * KN / 256), dim3(256), 0, stream>>>(
      h, W2, part, nbrs, nnbr, rcount, rlist);
  k_reduce<<<dim3((N3 * 16 / 4 + 255) / 256), dim3(256), 0, stream>>>(part, b2, xq);
  k_rot<<<dim3(NV / 16), dim3(256), 0, stream>>>(
      xq, wmat, area, nbrs, nnbr, ownG, gEdge, out);
  k_scatter<<<dim3(NV * 16 / 256 + NT), dim3(256), 0, stream>>>(
      gEdge, ownG, rcount, rlist, W2, part, grecon);
  k_mlp2_bwd<<<dim3(16, 32), dim3(256), 0, stream>>>(grecon, W2, gh);
  k_mlp1_bwd<<<dim3(B_, 8), dim3(256), 0, stream>>>(gh, h, W1, out + B_);
}

// Round 14
// 561.178 us; speedup vs baseline: 1.0826x; 1.0826x over previous
//
#include <hip/hip_runtime.h>

// Problem constants (from reference)
constexpr int B_ = 16;
constexpr int NV = 20000;      // N vertices
constexpr int KN = 16;         // K neighbors
constexpr int LAT = 256;       // LATENT
constexpr int HID = 1024;      // HIDDEN
constexpr int N3 = 60000;      // N*3
constexpr int RCAP = 64;       // reverse-adjacency capacity
constexpr int NCHUNK = 8;      // K-split for mlp2 (1024/128)
constexpr float INV_NK = 1.0f / (20000.0f * 16.0f);

// Workspace layout (float units)
constexpr size_t H_OFF      = 0;                             // h      [16][1024]
constexpr size_t XQ_OFF     = H_OFF + B_ * HID;              // xq     [20000][6][16] (x0..x2,q0..q2)
constexpr size_t GRECON_OFF = XQ_OFF + (size_t)NV * 96;      // g_recon[16][60000]
constexpr size_t GH_OFF     = GRECON_OFF + (size_t)B_ * N3;  // g_h    [16][1024]
constexpr size_t OWNG_OFF   = GH_OFF + B_ * HID;             // ownG   [20000][16][4]
constexpr size_t GEDGE_OFF  = OWNG_OFF + (size_t)NV * 64;    // gEdge  [20000][16][16][4]
constexpr size_t RCOUNT_OFF = GEDGE_OFF + (size_t)NV * KN * 64; // int [20000]
constexpr size_t RLIST_OFF  = RCOUNT_OFF + NV;               // int   [20000][64]
constexpr size_t PART_OFF   = RLIST_OFF + (size_t)NV * RCAP; // [8][60000][16]

__device__ __forceinline__ void atomAddF(float* p, float v) {
  unsafeAtomicAdd(p, v);   // hardware global_atomic_add_f32 on gfx950
}

// ---------------- fused prep: xpose -> xq, mlp1, zero gh/out/rcount ----------------
// block ranges: [0,938) xpose, [938,1002) mlp1, [1002,1006) zero gh,
//               1006 zero out, [1007,1086) zero rcount
__global__ __launch_bounds__(256) void k_prep(
    const float* __restrict__ xyz, const float* __restrict__ code,
    const float* __restrict__ W1, const float* __restrict__ b1,
    float* __restrict__ xq, float* __restrict__ h,
    float* __restrict__ gh, float* __restrict__ out,
    int* __restrict__ rcount) {
  const int bid = blockIdx.x, tid = threadIdx.x;
  if (bid < 938) {                              // transpose xyz -> xq x-part
    __shared__ float sm[64][17];
    const int n30 = bid * 64;
    {
      const int n3l = tid & 63, bq = tid >> 6;
      #pragma unroll
      for (int p = 0; p < 4; ++p) {
        int b = p * 4 + bq;
        if (n30 + n3l < N3) sm[n3l][b] = xyz[(size_t)b * N3 + n30 + n3l];
      }
    }
    __syncthreads();
    {
      const int b = tid & 15, nq = tid >> 4;
      #pragma unroll
      for (int p = 0; p < 4; ++p) {
        int n3 = n30 + p * 16 + nq;
        if (n3 < N3) {
          int n = n3 / 3, c = n3 - n * 3;
          xq[(size_t)n * 96 + c * 16 + b] = sm[p * 16 + nq][b];
        }
      }
    }
  } else if (bid < 1002) {                      // h = relu(code @ W1 + b1)
    int t = (bid - 938) * 256 + tid;            // 0..16383
    int b = t >> 10, hd = t & 1023;
    const float* c = code + b * LAT;
    float acc = b1[hd];
    #pragma unroll 4
    for (int l = 0; l < LAT; ++l) acc += c[l] * W1[l * HID + hd];
    h[t] = fmaxf(acc, 0.0f);
  } else if (bid < 1006) {                      // zero gh (16384 floats)
    int base = (bid - 1002) * 4096 + tid;
    #pragma unroll
    for (int r = 0; r < 16; ++r) gh[base + r * 256] = 0.0f;
  } else if (bid == 1006) {                     // zero out (16 + 4096 floats)
    for (int i = tid; i < B_ + B_ * LAT; i += 256) out[i] = 0.0f;
  } else {                                      // zero rcount (20000 ints)
    int i = (bid - 1007) * 256 + tid;
    if (i < NV) rcount[i] = 0;
  }
}

// ---------------- mlp2 partials + reverse-adjacency fill (independent work) ----------------
// blocks [0,472): part[chunk][j][b] = h-chunk @ W2-chunk ; blocks [472,1722): fill
__global__ __launch_bounds__(256) void k_mlp2f(
    const float* __restrict__ h, const float* __restrict__ W2,
    float* __restrict__ part,
    const int* __restrict__ nbrs, const int* __restrict__ nnbr,
    int* __restrict__ rcount, int* __restrict__ rlist) {
  const int bid = blockIdx.x;
  const int tid = threadIdx.x;
  if (bid >= 472) {                             // reverse adjacency fill
    int e = (bid - 472) * 256 + tid;            // 0..319999
    int n = e >> 4, k = e & 15;
    if (k < nnbr[n]) {
      int v = nbrs[e];
      int slot = atomicAdd(&rcount[v], 1);
      if (slot < RCAP) rlist[v * RCAP + slot] = e;
    }
    return;
  }
  const int bx = bid % 59, by = bid / 59;
  __shared__ float hs[16][128];
  const int hd0 = by * 128;
  #pragma unroll
  for (int r = 0; r < 8; ++r) {                 // stage h[0:16][hd0:hd0+128]
    int idx = r * 256 + tid;
    int bb = idx >> 7, cc = idx & 127;
    hs[bb][cc] = h[bb * HID + hd0 + cc];
  }
  __syncthreads();

  const int j4 = bx * 1024 + tid * 4;
  if (j4 >= N3) return;

  float4 acc[16];
  #pragma unroll
  for (int b = 0; b < 16; ++b) acc[b] = make_float4(0.f, 0.f, 0.f, 0.f);

  const float* wp = W2 + (size_t)hd0 * N3 + j4;
  float4 w0 = *(const float4*)(wp);
  float4 w1 = *(const float4*)(wp + (size_t)N3);
  float4 w2 = *(const float4*)(wp + (size_t)2 * N3);
  float4 w3 = *(const float4*)(wp + (size_t)3 * N3);

  for (int g = 0; g < 32; ++g) {
    const float* np = wp + (size_t)4 * N3;
    float4 n0, n1, n2, n3;
    if (g < 31) {                               // prefetch next 4 rows
      n0 = *(const float4*)(np);
      n1 = *(const float4*)(np + (size_t)N3);
      n2 = *(const float4*)(np + (size_t)2 * N3);
      n3 = *(const float4*)(np + (size_t)3 * N3);
    }
    #pragma unroll
    for (int b = 0; b < 16; ++b) {
      float4 hb = *(const float4*)&hs[b][g * 4];   // broadcast ds_read_b128
      acc[b].x += hb.x * w0.x + hb.y * w1.x + hb.z * w2.x + hb.w * w3.x;
      acc[b].y += hb.x * w0.y + hb.y * w1.y + hb.z * w2.y + hb.w * w3.y;
      acc[b].z += hb.x * w0.z + hb.y * w1.z + hb.z * w2.z + hb.w * w3.z;
      acc[b].w += hb.x * w0.w + hb.y * w1.w + hb.z * w2.w + hb.w * w3.w;
    }
    wp = np; w0 = n0; w1 = n1; w2 = n2; w3 = n3;
  }

  float ac[4][16];
  #pragma unroll
  for (int b = 0; b < 16; ++b) {
    ac[0][b] = acc[b].x; ac[1][b] = acc[b].y;
    ac[2][b] = acc[b].z; ac[3][b] = acc[b].w;
  }
  float* pbase = part + ((size_t)by * N3 + j4) * 16;
  #pragma unroll
  for (int jj = 0; jj < 4; ++jj)
    #pragma unroll
    for (int q = 0; q < 4; ++q)
      *(float4*)(pbase + jj * 16 + q * 4) = make_float4(
          ac[jj][q*4+0], ac[jj][q*4+1], ac[jj][q*4+2], ac[jj][q*4+3]);
}

// ---------------- xq q-part[j][b] = sum_c part[c][j][b] + b2[j] ----------------
__global__ __launch_bounds__(256) void k_reduce(
    const float* __restrict__ part, const float* __restrict__ b2,
    float* __restrict__ xq) {
  int t = blockIdx.x * 256 + threadIdx.x;       // one float4 each
  if (t >= N3 * 16 / 4) return;
  size_t pos = (size_t)t * 4;
  int j = t >> 2, bq = (t & 3) * 4;
  float4 s = *(const float4*)(part + pos);
  #pragma unroll
  for (int c = 1; c < NCHUNK; ++c) {
    float4 p = *(const float4*)(part + (size_t)c * N3 * 16 + pos);
    s.x += p.x; s.y += p.y; s.z += p.z; s.w += p.w;
  }
  float bias = b2[j];
  s.x += bias; s.y += bias; s.z += bias; s.w += bias;
  int n = j / 3, c = j - n * 3;
  *(float4*)(xq + (size_t)n * 96 + (3 + c) * 16 + bq) = s;
}

// ---------------- per-vertex: S, Jacobi->R, energy, per-edge grad store ----------------
// Array-free two-pass: pass 1 accumulates S only; pass 2 RE-GATHERS xq/nbrs/wmat
// (L2/L3-hot) and computes resid/energy/grads. VGPR ~90 -> 4 waves/EU residency.
__global__ __launch_bounds__(256, 4) void k_rot(
    const float* __restrict__ xq,
    const float* __restrict__ wmat, const float* __restrict__ area,
    const int* __restrict__ nbrs, const int* __restrict__ nnbr,
    float* __restrict__ ownG, float* __restrict__ gEdge,
    float* __restrict__ energy) {
  __shared__ float red[64];
  const int tid = threadIdx.x;
  const int b = tid & 15, nl = tid >> 4;
  const int n = blockIdx.x * 16 + nl;           // grid 1250 -> exactly 20000
  const int nn = nnbr[n];
  const float ar = area[n];
  const float* xqn = xq + (size_t)n * 96 + b;
  const float x0 = xqn[0],  x1 = xqn[16], x2 = xqn[32];
  const float q0 = xqn[48], q1 = xqn[64], q2 = xqn[80];

  // pass 1: covariance S (no per-k state kept)
  float S00=0,S01=0,S02=0,S10=0,S11=0,S12=0,S20=0,S21=0,S22=0;
  #pragma unroll
  for (int k = 0; k < KN; ++k) {
    if (k < nn) {
      int m = nbrs[n * KN + k];                 // broadcast across 16 b-lanes
      float w = wmat[n * KN + k];
      const float* mp = xq + (size_t)m * 96 + b;
      float dx = x0 - mp[0],  dy = x1 - mp[16], dz = x2 - mp[32];
      float ex = q0 - mp[48], ey = q1 - mp[64], ez = q2 - mp[80];
      S00 += w*dx*ex; S01 += w*dx*ey; S02 += w*dx*ez;
      S10 += w*dy*ex; S11 += w*dy*ey; S12 += w*dy*ez;
      S20 += w*dz*ex; S21 += w*dz*ey; S22 += w*dz*ez;
    }
  }

  float A00 = S00*S00 + S10*S10 + S20*S20;
  float A01 = S00*S01 + S10*S11 + S20*S21;
  float A02 = S00*S02 + S10*S12 + S20*S22;
  float A11 = S01*S01 + S11*S11 + S21*S21;
  float A12 = S01*S02 + S11*S12 + S21*S22;
  float A22 = S02*S02 + S12*S12 + S22*S22;
  float V00=1,V01=0,V02=0, V10=0,V11=1,V12=0, V20=0,V21=0,V22=1;

  auto rot = [&](float& app, float& aqq, float& apq, float& arp, float& arq,
                 float& vp0, float& vp1, float& vp2,
                 float& vq0, float& vq1, float& vq2) {
    float a = apq;
    if (fabsf(a) > 1e-37f) {
      float tau = (aqq - app) * 0.5f / a;
      float t = copysignf(1.0f, tau) / (fabsf(tau) + sqrtf(1.0f + tau * tau));
      float c = rsqrtf(1.0f + t * t);
      float s = t * c;
      float napp = c*c*app - 2.0f*s*c*a + s*s*aqq;
      float naqq = s*s*app + 2.0f*s*c*a + c*c*aqq;
      app = napp; aqq = naqq; apq = 0.0f;
      float rp = arp, rq = arq;
      arp = c*rp - s*rq; arq = s*rp + c*rq;
      float t0, t1;
      t0=vp0; t1=vq0; vp0 = c*t0 - s*t1; vq0 = s*t0 + c*t1;
      t0=vp1; t1=vq1; vp1 = c*t0 - s*t1; vq1 = s*t0 + c*t1;
      t0=vp2; t1=vq2; vp2 = c*t0 - s*t1; vq2 = s*t0 + c*t1;
    }
  };
  #pragma unroll
  for (int sweep = 0; sweep < 6; ++sweep) {
    rot(A00,A11,A01, A02,A12, V00,V10,V20, V01,V11,V21);
    rot(A00,A22,A02, A01,A12, V00,V10,V20, V02,V12,V22);
    rot(A11,A22,A12, A01,A02, V01,V11,V21, V02,V12,V22);
  }
  auto sw = [](float& a, float& c) { float t = a; a = c; c = t; };
  if (A00 < A11) { sw(A00,A11); sw(V00,V01); sw(V10,V11); sw(V20,V21); }
  if (A00 < A22) { sw(A00,A22); sw(V00,V02); sw(V10,V12); sw(V20,V22); }
  if (A11 < A22) { sw(A11,A22); sw(V01,V02); sw(V11,V12); sw(V21,V22); }

  float v1x=V00, v1y=V10, v1z=V20;
  float v2x=V01, v2y=V11, v2z=V21;

  float u1x = S00*v1x + S01*v1y + S02*v1z;
  float u1y = S10*v1x + S11*v1y + S12*v1z;
  float u1z = S20*v1x + S21*v1y + S22*v1z;
  float s1sq = u1x*u1x + u1y*u1y + u1z*u1z;
  if (s1sq > 1e-30f) { float r = rsqrtf(s1sq); u1x*=r; u1y*=r; u1z*=r; }
  else { u1x = 1.0f; u1y = 0.0f; u1z = 0.0f; }

  float u2x = S00*v2x + S01*v2y + S02*v2z;
  float u2y = S10*v2x + S11*v2y + S12*v2z;
  float u2z = S20*v2x + S21*v2y + S22*v2z;
  float pr = u2x*u1x + u2y*u1y + u2z*u1z;
  u2x -= pr*u1x; u2y -= pr*u1y; u2z -= pr*u1z;
  float s2sq = u2x*u2x + u2y*u2y + u2z*u2z;
  if (s2sq > 1e-12f * s1sq + 1e-30f) {
    float r = rsqrtf(s2sq); u2x*=r; u2y*=r; u2z*=r;
  } else {
    float ex_ = (fabsf(u1x) < 0.9f) ? 1.0f : 0.0f;
    float ey_ = 1.0f - ex_;
    float pp = ex_*u1x + ey_*u1y;
    u2x = ex_ - pp*u1x; u2y = ey_ - pp*u1y; u2z = -pp*u1z;
    float r = rsqrtf(u2x*u2x + u2y*u2y + u2z*u2z);
    u2x*=r; u2y*=r; u2z*=r;
  }
  float u3x = u1y*u2z - u1z*u2y, u3y = u1z*u2x - u1x*u2z, u3z = u1x*u2y - u1y*u2x;
  float v3x = v1y*v2z - v1z*v2y, v3y = v1z*v2x - v1x*v2z, v3z = v1x*v2y - v1y*v2x;

  float R00 = v1x*u1x + v2x*u2x + v3x*u3x;
  float R01 = v1x*u1y + v2x*u2y + v3x*u3y;
  float R02 = v1x*u1z + v2x*u2z + v3x*u3z;
  float R10 = v1y*u1x + v2y*u2x + v3y*u3x;
  float R11 = v1y*u1y + v2y*u2y + v3y*u3y;
  float R12 = v1y*u1z + v2y*u2z + v3y*u3z;
  float R20 = v1z*u1x + v2z*u2x + v3z*u3x;
  float R21 = v1z*u1y + v2z*u2y + v3z*u3y;
  float R22 = v1z*u1z + v2z*u2z + v3z*u3z;

  // pass 2: re-gather (cache-hot), residuals, energy, per-edge + own grads
  float esum = 0, go0 = 0, go1 = 0, go2 = 0;
  const float gf = 2.0f * ar * INV_NK;
  float* geb = gEdge + (size_t)n * 1024 + b * 4;   // [n][k][b][4]
  #pragma unroll
  for (int k = 0; k < KN; ++k) {
    if (k < nn) {
      int m = nbrs[n * KN + k];
      float w = wmat[n * KN + k];
      const float* mp = xq + (size_t)m * 96 + b;
      float dx = x0 - mp[0],  dy = x1 - mp[16], dz = x2 - mp[32];
      float ex = q0 - mp[48], ey = q1 - mp[64], ez = q2 - mp[80];
      float rx = ex - (R00*dx + R01*dy + R02*dz);
      float ry = ey - (R10*dx + R11*dy + R12*dz);
      float rz = ez - (R20*dx + R21*dy + R22*dz);
      esum += w * (rx*rx + ry*ry + rz*rz);
      float gc = gf * w;
      float gx = gc*rx, gy = gc*ry, gz = gc*rz;
      go0 += gx; go1 += gy; go2 += gz;
      *(float4*)(geb + k * 64) = make_float4(gx, gy, gz, 0.0f);
    }
  }
  esum *= ar * INV_NK;

  // own-gradient store: ownG[n][b][4]
  *(float4*)(ownG + (size_t)n * 64 + b * 4) = make_float4(go0, go1, go2, 0.0f);

  esum += __shfl_down(esum, 32);
  esum += __shfl_down(esum, 16);
  int wave = tid >> 6, lane = tid & 63;
  if (lane < 16) red[wave * 16 + lane] = esum;
  __syncthreads();
  if (tid < 16) atomAddF(&energy[tid], red[tid] + red[16 + tid] + red[32 + tid] + red[48 + tid]);
}

// ---------------- gather incoming edge grads (precomputed), final g_recon ----------------
__global__ __launch_bounds__(256) void k_scatter(
    const float* __restrict__ gEdge, const float* __restrict__ ownG,
    const int* __restrict__ rcount, const int* __restrict__ rlist,
    float* __restrict__ grecon) {
  int t = blockIdx.x * 256 + threadIdx.x;       // 20000*16 threads
  int v = t >> 4, b = t & 15;
  const float4 og = *(const float4*)(ownG + (size_t)v * 64 + b * 4);
  float g0 = og.x, g1 = og.y, g2 = og.z;
  int deg = min(rcount[v], RCAP);
  const int* rl = rlist + v * RCAP;
  int i = 0;
  for (; i + 3 < deg; i += 4) {                 // 4-wide for ILP
    int e0 = rl[i], e1 = rl[i + 1], e2 = rl[i + 2], e3 = rl[i + 3];
    float4 p0 = *(const float4*)(gEdge + (size_t)e0 * 64 + b * 4);
    float4 p1 = *(const float4*)(gEdge + (size_t)e1 * 64 + b * 4);
    float4 p2 = *(const float4*)(gEdge + (size_t)e2 * 64 + b * 4);
    float4 p3 = *(const float4*)(gEdge + (size_t)e3 * 64 + b * 4);
    g0 -= (p0.x + p1.x) + (p2.x + p3.x);
    g1 -= (p0.y + p1.y) + (p2.y + p3.y);
    g2 -= (p0.z + p1.z) + (p2.z + p3.z);
  }
  for (; i < deg; ++i) {
    int e = rl[i];
    float4 p = *(const float4*)(gEdge + (size_t)e * 64 + b * 4);
    g0 -= p.x; g1 -= p.y; g2 -= p.z;
  }
  float* gq = grecon + (size_t)b * N3 + v * 3;
  gq[0] = g0; gq[1] = g1; gq[2] = g2;
}

// ---------------- g_h = g_recon @ W2^T (round-1 body, best measured ~115 us) -------------
__global__ __launch_bounds__(256, 2) void k_mlp2_bwd(
    const float* __restrict__ gr, const float* __restrict__ W2,
    float* __restrict__ gh) {
  const int tid = threadIdx.x;
  const int lane = tid & 63;
  const int wv = tid >> 6;
  const int laneJ = lane & 15, laneR = lane >> 4;
  const int row0 = blockIdx.y * 32 + wv * 8 + laneR * 2;   // rows row0, row0+1

  float4 acc0[16], acc1[16];
  #pragma unroll
  for (int b = 0; b < 16; ++b) {
    acc0[b] = make_float4(0.f, 0.f, 0.f, 0.f);
    acc1[b] = make_float4(0.f, 0.f, 0.f, 0.f);
  }

  const int jbase = blockIdx.x * 64 + laneJ * 4;
  const float* w2r0 = W2 + (size_t)row0 * N3;
  const float* w2r1 = W2 + (size_t)(row0 + 1) * N3;

  for (int it = 0; it < 59; ++it) {
    int j = jbase + it * 1024;
    if (j < N3) {
      float4 w0 = *(const float4*)(w2r0 + j);
      float4 w1 = *(const float4*)(w2r1 + j);
      #pragma unroll
      for (int b = 0; b < 16; ++b) {
        float4 g = *(const float4*)(gr + (size_t)b * N3 + j);
        acc0[b].x += g.x * w0.x; acc0[b].y += g.y * w0.y;
        acc0[b].z += g.z * w0.z; acc0[b].w += g.w * w0.w;
        acc1[b].x += g.x * w1.x; acc1[b].y += g.y * w1.y;
        acc1[b].z += g.z * w1.z; acc1[b].w += g.w * w1.w;
      }
    }
  }

  float s0[16], s1[16];
  #pragma unroll
  for (int b = 0; b < 16; ++b) {
    s0[b] = (acc0[b].x + acc0[b].y) + (acc0[b].z + acc0[b].w);
    s1[b] = (acc1[b].x + acc1[b].y) + (acc1[b].z + acc1[b].w);
  }
  #pragma unroll
  for (int m = 1; m <= 8; m <<= 1) {
    #pragma unroll
    for (int b = 0; b < 16; ++b) {
      s0[b] += __shfl_xor(s0[b], m);
      s1[b] += __shfl_xor(s1[b], m);
    }
  }
  if (laneJ == 0) {
    #pragma unroll
    for (int b = 0; b < 16; ++b) {
      atomAddF(&gh[b * HID + row0], s0[b]);
      atomAddF(&gh[b * HID + row0 + 1], s1[b]);
    }
  }
}

// ---------------- g_code = (g_h * relu') @ W1^T ----------------
__global__ __launch_bounds__(256) void k_mlp1_bwd(
    const float* __restrict__ gh, const float* __restrict__ h,
    const float* __restrict__ W1, float* __restrict__ gcode) {
  __shared__ float gm[128];
  const int b = blockIdx.x;
  const int hd0 = blockIdx.y * 128;
  const int l = threadIdx.x;
  if (l < 128) {
    float g = gh[b * HID + hd0 + l];
    gm[l] = (h[b * HID + hd0 + l] > 0.0f) ? g : 0.0f;
  }
  __syncthreads();
  const float4* wp = (const float4*)(W1 + (size_t)l * HID + hd0);
  float acc = 0.0f;
  #pragma unroll
  for (int i = 0; i < 32; ++i) {
    float4 w4 = wp[i];
    acc += w4.x * gm[i*4+0] + w4.y * gm[i*4+1] + w4.z * gm[i*4+2] + w4.w * gm[i*4+3];
  }
  atomAddF(&gcode[b * LAT + l], acc);
}

extern "C" void kernel_launch(void* const* d_in, const int* in_sizes, int n_in,
                              void* d_out, int out_size, void* d_ws, size_t ws_size,
                              hipStream_t stream) {
  const float* code = (const float*)d_in[0];
  const float* W1   = (const float*)d_in[1];
  const float* b1   = (const float*)d_in[2];
  const float* W2   = (const float*)d_in[3];
  const float* b2   = (const float*)d_in[4];
  const float* xyz  = (const float*)d_in[5];
  const float* wmat = (const float*)d_in[6];
  const float* area = (const float*)d_in[7];
  const int* nbrs   = (const int*)d_in[8];
  const int* nnbr   = (const int*)d_in[9];

  float* out = (float*)d_out;           // [16] meanEnergy, [16*256] code_grad
  float* ws = (float*)d_ws;
  float* h      = ws + H_OFF;
  float* xq     = ws + XQ_OFF;
  float* grecon = ws + GRECON_OFF;
  float* gh     = ws + GH_OFF;
  float* ownG   = ws + OWNG_OFF;
  float* gEdge  = ws + GEDGE_OFF;
  int*   rcount = (int*)(ws + RCOUNT_OFF);
  int*   rlist  = (int*)(ws + RLIST_OFF);
  float* part   = ws + PART_OFF;

  // 7 dispatches, no memsets (zeroing folded into k_prep)
  k_prep<<<dim3(1086), dim3(256), 0, stream>>>(xyz, code, W1, b1, xq, h, gh, out, rcount);
  k_mlp2f<<<dim3(472 + NV * KN / 256), dim3(256), 0, stream>>>(
      h, W2, part, nbrs, nnbr, rcount, rlist);
  k_reduce<<<dim3((N3 * 16 / 4 + 255) / 256), dim3(256), 0, stream>>>(part, b2, xq);
  k_rot<<<dim3(NV / 16), dim3(256), 0, stream>>>(
      xq, wmat, area, nbrs, nnbr, ownG, gEdge, out);
  k_scatter<<<dim3(NV * 16 / 256), dim3(256), 0, stream>>>(
      gEdge, ownG, rcount, rlist, grecon);
  k_mlp2_bwd<<<dim3(16, 32), dim3(256), 0, stream>>>(grecon, W2, gh);
  k_mlp1_bwd<<<dim3(B_, 8), dim3(256), 0, stream>>>(gh, h, W1, out + B_);
}